// Round 5
// baseline (24106.277 us; speedup 1.0000x reference)
//
#include <hip/hip_runtime.h>

static constexpr int T_STEPS = 512;
static constexpr int BATCH   = 64;
static constexpr int DIN     = 256;
static constexpr int HID     = 512;
static constexpr int KDIM    = DIN + HID;   // 768
static constexpr int S4      = 193;         // LDS row stride in float4 (192 data + 1 pad)
static constexpr int NBLK    = 256;
static constexpr int NPROD   = 64;          // producers (kslices) per bgroup

__device__ __forceinline__ float fast_sigmoid(float v) {
    return 1.0f / (1.0f + __expf(-v));
}
__device__ __forceinline__ float fast_tanh(float v) {
    return 1.0f - 2.0f / (__expf(2.0f * v) + 1.0f);
}

// Relaxed agent-scope ops: L1+L2 bypass, served at MALL (device coherence
// point). No buffer_wbl2 / buffer_inv anywhere (rounds 1-3 lesson).
__device__ __forceinline__ void store_bypass(float* p, float v) {
    __hip_atomic_store((unsigned int*)p, __float_as_uint(v),
                       __ATOMIC_RELAXED, __HIP_MEMORY_SCOPE_AGENT);
}
__device__ __forceinline__ float load_bypass(const float* p) {
    return __uint_as_float(__hip_atomic_load((const unsigned int*)p,
                           __ATOMIC_RELAXED, __HIP_MEMORY_SCOPE_AGENT));
}

// Round-5 core change: ONE counter word per bgroup, ONE polling lane per WG,
// s_sleep(8) (~0.2 us) pacing. Keeps MALL request queues shallow so the
// dependency chain isn't stuck behind a poll storm (rounds 2-4's failure).
__device__ __forceinline__ void wait_cnt(const unsigned* __restrict__ cnt,
                                         unsigned target) {
    if (threadIdx.x == 0) {
        while (__hip_atomic_load(cnt, __ATOMIC_RELAXED,
                                 __HIP_MEMORY_SCOPE_AGENT) < target) {
            __builtin_amdgcn_s_sleep(8);
        }
    }
    __syncthreads();   // full compiler/exec barrier: gather can't hoist above
}

// 256 WGs x 512 threads, 1 WG/CU. Each WG: batch group of 16 (bgroup 0..3),
// hidden slice of 8 units (kslice 0..63). Weights LDS-resident all 512 steps;
// c in registers; h ping-pongs through the hx/cx tail of d_out via MALL-bypass
// ops only (no cached copies of those lines ever exist during the recurrence).
__global__ __launch_bounds__(512, 1)
void lstm_persistent(const float* __restrict__ x,
                     const float* __restrict__ Wf, const float* __restrict__ bfp,
                     const float* __restrict__ Wi, const float* __restrict__ bip,
                     const float* __restrict__ Wg, const float* __restrict__ bgp,
                     const float* __restrict__ Wo, const float* __restrict__ bop,
                     float* __restrict__ out, unsigned* __restrict__ cnt_ws) {
    __shared__ float4 W4[32 * S4];        // 32 rows x 768 fp32
    __shared__ float4 C4[16 * S4];        // combined [x|h] for 16 b
    __shared__ float  gates_s[16 * 33];
    __shared__ float  bias_s[32];

    const int tid = threadIdx.x;
    const int wg  = blockIdx.x;
    // Round-robin dispatch heuristic: bgroup g on XCD pair {2g,2g+1} (perf only).
    const int bgroup = (wg & 7) >> 1;                  // 0..3
    const int kslice = ((wg >> 3) << 1) | (wg & 1);    // 0..63
    const int bg0 = bgroup * 16;
    const int k0  = kslice * 8;

    unsigned* const cnt = cnt_ws + bgroup * 32;        // counters 128 B apart

    // ---- one-time: stage 32 weight rows (gate*8 + unit) into LDS ----
    {
        const int r    = tid >> 4;     // 0..31
        const int c0   = tid & 15;
        const int gate = r >> 3;
        const int unit = k0 + (r & 7);
        const float* wsrc = (gate == 0) ? Wf : (gate == 1) ? Wi : (gate == 2) ? Wg : Wo;
        const float4* src4 = (const float4*)(wsrc + (size_t)unit * KDIM);
        #pragma unroll
        for (int m = 0; m < 12; ++m)
            W4[r * S4 + c0 + 16 * m] = src4[c0 + 16 * m];
        if (tid < 32) {
            const int g2 = tid >> 3;
            const float* bsrc = (g2 == 0) ? bfp : (g2 == 1) ? bip : (g2 == 2) ? bgp : bop;
            bias_s[tid] = bsrc[k0 + (tid & 7)];
        }
    }

    float* const hx_sec = out + (size_t)T_STEPS * BATCH * HID;  // buf0 (ends as hx)
    float* const cx_sec = hx_sec + BATCH * HID;                 // buf1 (ends as cx)

    const int lb2 = tid >> 3;   // cell-update mapping (tid<128)
    const int u2  = tid & 7;

    // zero h0 slab via bypass stores; publish (+1). __syncthreads drains
    // vmcnt(0) before s_barrier -> h stores at MALL before the add issues.
    if (tid < 128)
        store_bypass(&hx_sec[(size_t)(bg0 + lb2) * HID + (k0 + u2)], 0.0f);
    __syncthreads();
    if (tid == 0)
        __hip_atomic_fetch_add(cnt, 1u, __ATOMIC_RELAXED,
                               __HIP_MEMORY_SCOPE_AGENT);

    // GEMM mapping: lane strip over K (16 interleaved f4 stripes), 4x4 tile
    const int lbg = tid >> 7;        // 0..3  -> batches lbg*4..+3
    const int rg  = (tid >> 4) & 7;  // 0..7  -> rows rg*4..+3
    const int kq  = tid & 15;        // 0..15 -> K stripe

    float c_reg = 0.0f;

    for (int t = 0; t < T_STEPS; ++t) {
        const float* h_read  = (t & 1) ? cx_sec : hx_sec;   // h_t in buf[t&1]
        float*       h_write = (t & 1) ? hx_sec : cx_sec;   // h_{t+1} -> buf[(t+1)&1]

        // ---- A: stage x_t (flag-independent; hides behind the poll) ----
        {
            const float4* xs = (const float4*)(x + ((size_t)t * BATCH + bg0) * DIN);
            #pragma unroll
            for (int m = 0; m < 2; ++m) {
                const int i4 = tid + 512 * m;               // 16b x 64 f4
                C4[(i4 >> 6) * S4 + (i4 & 63)] = xs[i4];
            }
        }

        // ---- B: wait until all 64 peers published h_t ----
        wait_cnt(cnt, (unsigned)(NPROD * (t + 1)));

        // ---- C: gather h_t via bypass loads (batch m, element tid) ----
        {
            const float* hsrc = h_read + (size_t)bg0 * HID;
            float hv[16];
            #pragma unroll
            for (int m = 0; m < 16; ++m)
                hv[m] = load_bypass(&hsrc[512 * m + tid]);
            float* Cf = (float*)C4;
            #pragma unroll
            for (int m = 0; m < 16; ++m)
                Cf[m * (S4 * 4) + 256 + tid] = hv[m];   // consecutive dwords: conflict-free
        }
        __syncthreads();

        // ---- D: gates GEMM: 4x4 register tile, K/16 per lane ----
        float acc[4][4];
        #pragma unroll
        for (int i = 0; i < 4; ++i)
            #pragma unroll
            for (int j = 0; j < 4; ++j) acc[i][j] = 0.0f;

        #pragma unroll
        for (int it = 0; it < 12; ++it) {
            const int dq = kq + 16 * it;
            float4 cv[4], wv[4];
            #pragma unroll
            for (int i = 0; i < 4; ++i) cv[i] = C4[(lbg * 4 + i) * S4 + dq];
            #pragma unroll
            for (int j = 0; j < 4; ++j) wv[j] = W4[(rg * 4 + j) * S4 + dq];
            #pragma unroll
            for (int i = 0; i < 4; ++i) {
                #pragma unroll
                for (int j = 0; j < 4; ++j) {
                    acc[i][j] = fmaf(cv[i].x, wv[j].x, acc[i][j]);
                    acc[i][j] = fmaf(cv[i].y, wv[j].y, acc[i][j]);
                    acc[i][j] = fmaf(cv[i].z, wv[j].z, acc[i][j]);
                    acc[i][j] = fmaf(cv[i].w, wv[j].w, acc[i][j]);
                }
            }
        }

        // ---- E: reduce 16 K-stripes via shuffle, park in LDS ----
        #pragma unroll
        for (int i = 0; i < 4; ++i) {
            #pragma unroll
            for (int j = 0; j < 4; ++j) {
                float v = acc[i][j];
                v += __shfl_xor(v, 1);
                v += __shfl_xor(v, 2);
                v += __shfl_xor(v, 4);
                v += __shfl_xor(v, 8);
                if (kq == 0)
                    gates_s[(lbg * 4 + i) * 33 + (rg * 4 + j)] = v;
            }
        }
        __syncthreads();

        // ---- F: LSTM cell update (one thread per (b, hidden unit)) ----
        if (tid < 128) {
            const float pf = gates_s[lb2 * 33 + u2]      + bias_s[u2];
            const float pi = gates_s[lb2 * 33 + 8 + u2]  + bias_s[8 + u2];
            const float pg = gates_s[lb2 * 33 + 16 + u2] + bias_s[16 + u2];
            const float po = gates_s[lb2 * 33 + 24 + u2] + bias_s[24 + u2];
            const float fg = fast_sigmoid(pf);
            const float ig = fast_sigmoid(pi);
            const float gg = fast_tanh(pg);
            const float og = fast_sigmoid(po);
            c_reg = fg * c_reg + ig * gg;
            const float h = og * fast_tanh(c_reg);
            const int b = bg0 + lb2;
            const int k = k0 + u2;
            store_bypass(&h_write[(size_t)b * HID + k], h);   // MALL-direct
            out[((size_t)t * BATCH + b) * HID + k] = h;       // cached, flushed at end
        }
        __syncthreads();   // drains vmcnt(0): h bypass stores visible at MALL

        // ---- G: publish h_{t+1}: one relaxed RMW (no cache maintenance) ----
        if (tid == 0)
            __hip_atomic_fetch_add(cnt, 1u, __ATOMIC_RELAXED,
                                   __HIP_MEMORY_SCOPE_AGENT);
    }

    // Final: hx (h_512) already at MALL in hx_sec. Overwrite buf1 (h_511) with
    // c only after all peers finished step 511 (cnt = 64*513 => done reading
    // h_511). Normal stores: flushed by end-of-kernel release.
    wait_cnt(cnt, (unsigned)(NPROD * (T_STEPS + 1)));
    if (tid < 128)
        cx_sec[(size_t)(bg0 + lb2) * HID + (k0 + u2)] = c_reg;
}

extern "C" void kernel_launch(void* const* d_in, const int* in_sizes, int n_in,
                              void* d_out, int out_size, void* d_ws, size_t ws_size,
                              hipStream_t stream) {
    (void)in_sizes; (void)n_in; (void)ws_size; (void)out_size;
    const float* x  = (const float*)d_in[0];
    const float* Wf = (const float*)d_in[1];
    const float* bf = (const float*)d_in[2];
    const float* Wi = (const float*)d_in[3];
    const float* bi = (const float*)d_in[4];
    const float* Wg = (const float*)d_in[5];
    const float* bg = (const float*)d_in[6];
    const float* Wo = (const float*)d_in[7];
    const float* bo = (const float*)d_in[8];
    float* out = (float*)d_out;
    unsigned* cnt = (unsigned*)d_ws;

    // counters[4] spaced 128 B apart; must start at 0 (d_ws poisoned 0xAA)
    hipMemsetAsync(d_ws, 0, 4 * 32 * sizeof(unsigned), stream);

    void* args[] = {&x, &Wf, &bf, &Wi, &bi, &Wg, &bg, &Wo, &bo, &out, &cnt};
    hipLaunchCooperativeKernel(reinterpret_cast<void*>(lstm_persistent),
                               dim3(NBLK), dim3(512), args, 0, stream);
}

// Round 6
// 5311.970 us; speedup vs baseline: 4.5381x; 4.5381x over previous
//
#include <hip/hip_runtime.h>

static constexpr int T_STEPS = 512;
static constexpr int BATCH   = 64;
static constexpr int DIN     = 256;
static constexpr int HID     = 512;
static constexpr int KDIM    = DIN + HID;   // 768
static constexpr int S4      = 193;         // LDS row stride in float4 (192 data + 1 pad)
static constexpr int NBLK    = 256;
static constexpr int NPROD   = 64;          // producers (kslices) per bgroup

__device__ __forceinline__ float fast_sigmoid(float v) {
    return 1.0f / (1.0f + __expf(-v));
}
__device__ __forceinline__ float fast_tanh(float v) {
    return 1.0f - 2.0f / (__expf(2.0f * v) + 1.0f);
}

// Relaxed agent-scope ops: L1+L2 bypass, served at the device coherence
// point. No buffer_wbl2 / buffer_inv anywhere (rounds 1-3 lesson: per-WG
// full-L2 writeback+invalidate is catastrophic).
__device__ __forceinline__ void store_bypass(float* p, float v) {
    __hip_atomic_store((unsigned int*)p, __float_as_uint(v),
                       __ATOMIC_RELAXED, __HIP_MEMORY_SCOPE_AGENT);
}
__device__ __forceinline__ float load_bypass(const float* p) {
    return __uint_as_float(__hip_atomic_load((const unsigned int*)p,
                           __ATOMIC_RELAXED, __HIP_MEMORY_SCOPE_AGENT));
}

// One counter word per bgroup, one polling lane per WG, paced s_sleep.
__device__ __forceinline__ void wait_cnt(const unsigned* __restrict__ cnt,
                                         unsigned target) {
    if (threadIdx.x == 0) {
        while (__hip_atomic_load(cnt, __ATOMIC_RELAXED,
                                 __HIP_MEMORY_SCOPE_AGENT) < target) {
            __builtin_amdgcn_s_sleep(4);
        }
    }
    __syncthreads();   // full compiler/exec barrier: gather can't hoist above
}

// 256 WGs x 512 threads, 1 WG/CU. Each WG: batch group of 16 (bgroup 0..3),
// hidden slice of 8 units (kslice 0..63). Weights LDS-resident all 512 steps;
// c in registers; h ping-pongs through the hx/cx tail of d_out via bypass ops.
// ROUND 6: K-loop unroll capped at 2. The previous full unroll (12) hoisted
// 12x(cv[4]+wv[4]) = 384 VGPRs of ds_read destinations -> spilled to scratch
// -> 32 WGs x ~300 KB scratch per XCD >> 4 MiB L2 -> 70 GB/launch of HBM
// spill traffic = the entire 24 ms wall (70 GB / 2.9 TB/s).
__global__ __launch_bounds__(512, 1)
void lstm_persistent(const float* __restrict__ x,
                     const float* __restrict__ Wf, const float* __restrict__ bfp,
                     const float* __restrict__ Wi, const float* __restrict__ bip,
                     const float* __restrict__ Wg, const float* __restrict__ bgp,
                     const float* __restrict__ Wo, const float* __restrict__ bop,
                     float* __restrict__ out, unsigned* __restrict__ cnt_ws) {
    __shared__ float4 W4[32 * S4];        // 32 rows x 768 fp32
    __shared__ float4 C4[16 * S4];        // combined [x|h] for 16 b
    __shared__ float  gates_s[16 * 33];
    __shared__ float  bias_s[32];

    const int tid = threadIdx.x;
    const int wg  = blockIdx.x;
    const int bgroup = (wg & 7) >> 1;                  // 0..3
    const int kslice = ((wg >> 3) << 1) | (wg & 1);    // 0..63
    const int bg0 = bgroup * 16;
    const int k0  = kslice * 8;

    unsigned* const cnt = cnt_ws + bgroup * 32;        // counters 128 B apart

    // ---- one-time: stage 32 weight rows (gate*8 + unit) into LDS ----
    {
        const int r    = tid >> 4;     // 0..31
        const int c0   = tid & 15;
        const int gate = r >> 3;
        const int unit = k0 + (r & 7);
        const float* wsrc = (gate == 0) ? Wf : (gate == 1) ? Wi : (gate == 2) ? Wg : Wo;
        const float4* src4 = (const float4*)(wsrc + (size_t)unit * KDIM);
        #pragma unroll 2
        for (int m = 0; m < 12; ++m)
            W4[r * S4 + c0 + 16 * m] = src4[c0 + 16 * m];
        if (tid < 32) {
            const int g2 = tid >> 3;
            const float* bsrc = (g2 == 0) ? bfp : (g2 == 1) ? bip : (g2 == 2) ? bgp : bop;
            bias_s[tid] = bsrc[k0 + (tid & 7)];
        }
    }

    float* const hx_sec = out + (size_t)T_STEPS * BATCH * HID;  // buf0 (ends as hx)
    float* const cx_sec = hx_sec + BATCH * HID;                 // buf1 (ends as cx)

    const int lb2 = tid >> 3;   // cell-update mapping (tid<128)
    const int u2  = tid & 7;

    // zero h0 slab via bypass stores; publish (+1). __syncthreads drains
    // vmcnt(0) before s_barrier -> h stores visible before the add issues.
    if (tid < 128)
        store_bypass(&hx_sec[(size_t)(bg0 + lb2) * HID + (k0 + u2)], 0.0f);
    __syncthreads();
    if (tid == 0)
        __hip_atomic_fetch_add(cnt, 1u, __ATOMIC_RELAXED,
                               __HIP_MEMORY_SCOPE_AGENT);

    // GEMM mapping: lane strip over K (16 interleaved f4 stripes), 4x4 tile
    const int lbg = tid >> 7;        // 0..3  -> batches lbg*4..+3
    const int rg  = (tid >> 4) & 7;  // 0..7  -> rows rg*4..+3
    const int kq  = tid & 15;        // 0..15 -> K stripe

    float c_reg = 0.0f;

    for (int t = 0; t < T_STEPS; ++t) {
        const float* h_read  = (t & 1) ? cx_sec : hx_sec;   // h_t in buf[t&1]
        float*       h_write = (t & 1) ? hx_sec : cx_sec;   // h_{t+1} -> buf[(t+1)&1]

        // ---- A: stage x_t (flag-independent; hides behind the poll) ----
        {
            const float4* xs = (const float4*)(x + ((size_t)t * BATCH + bg0) * DIN);
            #pragma unroll
            for (int m = 0; m < 2; ++m) {
                const int i4 = tid + 512 * m;               // 16b x 64 f4
                C4[(i4 >> 6) * S4 + (i4 & 63)] = xs[i4];
            }
        }

        // ---- B: wait until all 64 peers published h_t ----
        wait_cnt(cnt, (unsigned)(NPROD * (t + 1)));

        // ---- C: gather h_t via bypass loads (batch m, element tid) ----
        {
            const float* hsrc = h_read + (size_t)bg0 * HID;
            float* Cf = (float*)C4;
            #pragma unroll 4
            for (int m = 0; m < 16; ++m) {
                const float hv = load_bypass(&hsrc[512 * m + tid]);
                Cf[m * (S4 * 4) + 256 + tid] = hv;   // consecutive dwords: conflict-free
            }
        }
        __syncthreads();

        // ---- D: gates GEMM: 4x4 register tile, K/16 per lane ----
        // unroll 2: live set ~ acc(16) + 2x(cv+wv)(64) + addr < 128 VGPRs.
        float acc[4][4];
        #pragma unroll
        for (int i = 0; i < 4; ++i)
            #pragma unroll
            for (int j = 0; j < 4; ++j) acc[i][j] = 0.0f;

        #pragma unroll 2
        for (int it = 0; it < 12; ++it) {
            const int dq = kq + 16 * it;
            float4 cv[4], wv[4];
            #pragma unroll
            for (int i = 0; i < 4; ++i) cv[i] = C4[(lbg * 4 + i) * S4 + dq];
            #pragma unroll
            for (int j = 0; j < 4; ++j) wv[j] = W4[(rg * 4 + j) * S4 + dq];
            #pragma unroll
            for (int i = 0; i < 4; ++i) {
                #pragma unroll
                for (int j = 0; j < 4; ++j) {
                    acc[i][j] = fmaf(cv[i].x, wv[j].x, acc[i][j]);
                    acc[i][j] = fmaf(cv[i].y, wv[j].y, acc[i][j]);
                    acc[i][j] = fmaf(cv[i].z, wv[j].z, acc[i][j]);
                    acc[i][j] = fmaf(cv[i].w, wv[j].w, acc[i][j]);
                }
            }
        }

        // ---- E: reduce 16 K-stripes via shuffle, park in LDS ----
        #pragma unroll
        for (int i = 0; i < 4; ++i) {
            #pragma unroll
            for (int j = 0; j < 4; ++j) {
                float v = acc[i][j];
                v += __shfl_xor(v, 1);
                v += __shfl_xor(v, 2);
                v += __shfl_xor(v, 4);
                v += __shfl_xor(v, 8);
                if (kq == 0)
                    gates_s[(lbg * 4 + i) * 33 + (rg * 4 + j)] = v;
            }
        }
        __syncthreads();

        // ---- F: LSTM cell update (one thread per (b, hidden unit)) ----
        if (tid < 128) {
            const float pf = gates_s[lb2 * 33 + u2]      + bias_s[u2];
            const float pi = gates_s[lb2 * 33 + 8 + u2]  + bias_s[8 + u2];
            const float pg = gates_s[lb2 * 33 + 16 + u2] + bias_s[16 + u2];
            const float po = gates_s[lb2 * 33 + 24 + u2] + bias_s[24 + u2];
            const float fg = fast_sigmoid(pf);
            const float ig = fast_sigmoid(pi);
            const float gg = fast_tanh(pg);
            const float og = fast_sigmoid(po);
            c_reg = fg * c_reg + ig * gg;
            const float h = og * fast_tanh(c_reg);
            const int b = bg0 + lb2;
            const int k = k0 + u2;
            store_bypass(&h_write[(size_t)b * HID + k], h);   // coherent-direct
            out[((size_t)t * BATCH + b) * HID + k] = h;       // cached, flushed at end
        }
        __syncthreads();   // drains vmcnt(0): h bypass stores globally visible

        // ---- G: publish h_{t+1}: one relaxed RMW (no cache maintenance) ----
        if (tid == 0)
            __hip_atomic_fetch_add(cnt, 1u, __ATOMIC_RELAXED,
                                   __HIP_MEMORY_SCOPE_AGENT);
    }

    // Final: hx (h_512) already in hx_sec. Overwrite buf1 (h_511) with c only
    // after all peers finished step 511 (cnt = 64*513 => done reading h_511).
    wait_cnt(cnt, (unsigned)(NPROD * (T_STEPS + 1)));
    if (tid < 128)
        cx_sec[(size_t)(bg0 + lb2) * HID + (k0 + u2)] = c_reg;
}

extern "C" void kernel_launch(void* const* d_in, const int* in_sizes, int n_in,
                              void* d_out, int out_size, void* d_ws, size_t ws_size,
                              hipStream_t stream) {
    (void)in_sizes; (void)n_in; (void)ws_size; (void)out_size;
    const float* x  = (const float*)d_in[0];
    const float* Wf = (const float*)d_in[1];
    const float* bf = (const float*)d_in[2];
    const float* Wi = (const float*)d_in[3];
    const float* bi = (const float*)d_in[4];
    const float* Wg = (const float*)d_in[5];
    const float* bg = (const float*)d_in[6];
    const float* Wo = (const float*)d_in[7];
    const float* bo = (const float*)d_in[8];
    float* out = (float*)d_out;
    unsigned* cnt = (unsigned*)d_ws;

    // counters[4] spaced 128 B apart; must start at 0 (d_ws poisoned 0xAA)
    hipMemsetAsync(d_ws, 0, 4 * 32 * sizeof(unsigned), stream);

    void* args[] = {&x, &Wf, &bf, &Wi, &bi, &Wg, &bg, &Wo, &bo, &out, &cnt};
    hipLaunchCooperativeKernel(reinterpret_cast<void*>(lstm_persistent),
                               dim3(NBLK), dim3(512), args, 0, stream);
}